// Round 7
// baseline (770.631 us; speedup 1.0000x reference)
//
#include <hip/hip_runtime.h>
#include <math.h>

// Problem constants: B=1024, T=256, D=128, H=64, 4H=256
constexpr int B_ = 1024;
constexpr int T_ = 256;
constexpr int D_ = 128;
constexpr int H_ = 64;
constexpr int BPB_ = 8;     // batches per block
constexpr int NBLK_ = B_ / BPB_;  // 128 blocks

typedef short  v8s __attribute__((ext_vector_type(8)));   // 8 bf16 (4 VGPRs)
typedef float  v4f __attribute__((ext_vector_type(4)));   // MFMA acc

__device__ __forceinline__ float sigmoidf_(float x) {
    return 1.0f / (1.0f + __expf(-x));
}
// tanh(x) = 2*sigmoid(2x) - 1 ; overflow-safe at both ends
__device__ __forceinline__ float tanhf_(float x) {
    return fmaf(2.0f, 1.0f / (1.0f + __expf(-2.0f * x)), -1.0f);
}
__device__ __forceinline__ unsigned short f2bf(float f) {   // RNE f32->bf16
    unsigned u = __float_as_uint(f);
    u = (u + 0x7fffu + ((u >> 16) & 1u)) >> 16;
    return (unsigned short)u;
}
__device__ __forceinline__ v8s pack8(float4 a, float4 b) {
    v8s r;
    r[0] = (short)f2bf(a.x); r[1] = (short)f2bf(a.y);
    r[2] = (short)f2bf(a.z); r[3] = (short)f2bf(a.w);
    r[4] = (short)f2bf(b.x); r[5] = (short)f2bf(b.y);
    r[6] = (short)f2bf(b.z); r[7] = (short)f2bf(b.w);
    return r;
}

// ---------------------------------------------------------------------------
// Producer/consumer LSTM. 128 blocks x 512 threads (8 waves), 8 batches/block.
//
// Waves 4-7 (producers): stream x (HBM, read once), MFMA-project through
//   W_ih (bias folded), write packed bf16 (i,f,g,o) per (batch, j) into a
//   double-buffered 8-step LDS window xpbuf. Never execute a block barrier
//   in the loop -> their HBM latency never lands on the serial chain.
// Waves 0-3 (consumers): serial recurrence touching ONLY LDS + registers.
//   Wave wv owns j in [16wv,16wv+16) (gate tiles cls*4+wv): i,f,g,o of a
//   (batch,j) pair sit in one lane's registers (MFMA C layout: col=lane&15
//   = batch, row = q*4+r = j within tile). Per-step sync = LDS spin counter
//   (monotonic) among the 4 consumer waves only.
// Window handshake: pcnt[slot] (producer fills done), ccnt[slot] (consumer
//   windows done), both monotonic, 4 increments (1/wave) per event.
// ---------------------------------------------------------------------------
__global__ __launch_bounds__(512, 2)
void lstm_pc_kernel(const float* __restrict__ x,     // [B,T,D]
                    const float* __restrict__ W_ih,  // [256,128]
                    const float* __restrict__ W_hh,  // [256,64]
                    const float* __restrict__ b_ih,  // [256]
                    const float* __restrict__ b_hh,  // [256]
                    const float* __restrict__ W1,    // [32,64]
                    const float* __restrict__ b1,    // [32]
                    const float* __restrict__ W2,    // [1,32]
                    const float* __restrict__ b2,    // [1]
                    float* __restrict__ out)         // [B]
{
    const int tid  = threadIdx.x;
    const int wv   = tid >> 6;          // 0..7
    const int lane = tid & 63;
    const int q    = lane >> 4;         // 0..3
    const int ml   = lane & 15;         // 0..15
    const int mlc  = ml & 7;            // consumer batch index (dup for ml>=8)

    // xp window: [slot][step][batch][j] ushort4(i,f,g,o); row 66 for 16B align
    __shared__ __align__(16) ushort4 xpbuf[2][8][BPB_][66];       // 67.6 KB
    __shared__ __align__(16) unsigned short hbf[2][16][72];       // 4.6 KB
    __shared__ __align__(16) float hf[16][68];                    // 4.3 KB
    __shared__ __align__(16) float ys[BPB_][36];                  // 1.2 KB
    __shared__ unsigned pcnt[2];   // producer fills done per slot (monotonic)
    __shared__ unsigned ccnt[2];   // consumer windows done per slot (monotonic)
    __shared__ unsigned hcnt;      // consumer per-step arrivals (monotonic)

    if (tid == 0) { pcnt[0] = 0; pcnt[1] = 0; ccnt[0] = 0; ccnt[1] = 0; hcnt = 0; }
    for (int i = tid; i < 2 * 16 * 72 / 2; i += 512) ((unsigned*)hbf)[i] = 0u;
    __syncthreads();   // ONLY barrier before the epilogue

    const float* __restrict__ xb = x + (size_t)(blockIdx.x * BPB_) * T_ * D_;

    if (wv >= 4) {
        // ================= PRODUCER =================
        const int pw = wv - 4;   // 0..3 : j-quarter [16pw,16pw+16)
        v8s wih[4][4];           // [cls][ks] A-frags of W_ih (m = gate)
        v4f bias[4];
        #pragma unroll
        for (int cls = 0; cls < 4; ++cls) {
            const int gr = (cls * 4 + pw) * 16 + ml;    // A m-index = ml
            #pragma unroll
            for (int ks = 0; ks < 4; ++ks) {
                const float* p = W_ih + (size_t)gr * D_ + ks * 32 + q * 8;
                wih[cls][ks] = pack8(((const float4*)p)[0], ((const float4*)p)[1]);
            }
            #pragma unroll
            for (int r = 0; r < 4; ++r) {
                const int g2 = (cls * 4 + pw) * 16 + q * 4 + r;  // C row=q*4+r
                bias[cls][r] = b_ih[g2] + b_hh[g2];
            }
        }

        for (int w = 0; w < 32; ++w) {
            const int s = w & 1, e = w >> 1;
            if (e >= 1) {   // wait until consumers released this slot
                const unsigned tgt = 4u * (unsigned)e;
                while (*(volatile const unsigned*)&ccnt[s] < tgt)
                    __builtin_amdgcn_s_sleep(1);
                __threadfence_block();   // acquire
            }
            #pragma unroll 2
            for (int tl = 0; tl < 8; ++tl) {
                const int t = w * 8 + tl;
                v4f acc[4];
                #pragma unroll
                for (int cls = 0; cls < 4; ++cls) acc[cls] = bias[cls];
                #pragma unroll
                for (int ks = 0; ks < 4; ++ks) {
                    v8s bfr;
                    if (ml < BPB_) {   // B[n=ml=batch][k=d]
                        const float* p = xb + ((size_t)ml * T_ + t) * D_
                                            + ks * 32 + q * 8;
                        bfr = pack8(((const float4*)p)[0], ((const float4*)p)[1]);
                    } else {
                        bfr = (v8s)(short)0;
                    }
                    #pragma unroll
                    for (int cls = 0; cls < 4; ++cls)
                        acc[cls] = __builtin_amdgcn_mfma_f32_16x16x32_bf16(
                            wih[cls][ks], bfr, acc[cls], 0, 0, 0);
                }
                if (ml < BPB_) {
                    #pragma unroll
                    for (int r = 0; r < 4; ++r) {
                        ushort4 p;
                        p.x = f2bf(acc[0][r]);   // i
                        p.y = f2bf(acc[1][r]);   // f
                        p.z = f2bf(acc[2][r]);   // g
                        p.w = f2bf(acc[3][r]);   // o
                        xpbuf[s][tl][ml][pw * 16 + q * 4 + r] = p;
                    }
                }
            }
            __threadfence_block();   // release: xp writes visible
            if (lane == 0) atomicAdd(&pcnt[s], 1u);
        }
    } else {
        // ================= CONSUMER =================
        v8s whh[4][2];   // [cls][ks] A-frags of W_hh
        #pragma unroll
        for (int cls = 0; cls < 4; ++cls) {
            const int gr = (cls * 4 + wv) * 16 + ml;
            #pragma unroll
            for (int ks = 0; ks < 2; ++ks) {
                const float* p = W_hh + (size_t)gr * H_ + ks * 32 + q * 8;
                whh[cls][ks] = pack8(((const float4*)p)[0], ((const float4*)p)[1]);
            }
        }

        float cst[4]   = {0.f, 0.f, 0.f, 0.f};
        float hlast[4] = {0.f, 0.f, 0.f, 0.f};

        for (int w = 0; w < 32; ++w) {
            const int s = w & 1, e = w >> 1;
            {   // wait until producers filled this slot for epoch e
                const unsigned tgt = 4u * (unsigned)(e + 1);
                while (*(volatile const unsigned*)&pcnt[s] < tgt)
                    __builtin_amdgcn_s_sleep(1);
                __threadfence_block();   // acquire
            }
            // prefetch step 0's xp
            uint4 A, Bv;
            {
                const uint4* xpp = (const uint4*)&xpbuf[s][0][mlc][wv * 16 + q * 4];
                A = xpp[0]; Bv = xpp[1];
            }
            #pragma unroll 2
            for (int tl = 0; tl < 8; ++tl) {
                const int t = w * 8 + tl;
                // h(t) reads (synced at end of previous step)
                v8s h0 = *(const v8s*)&hbf[tl & 1][ml][q * 8];
                v8s h1 = *(const v8s*)&hbf[tl & 1][ml][32 + q * 8];
                // prefetch next step's xp (window-valid, no step sync needed)
                uint4 An, Bn;
                if (tl < 7) {
                    const uint4* xpp =
                        (const uint4*)&xpbuf[s][tl + 1][mlc][wv * 16 + q * 4];
                    An = xpp[0]; Bn = xpp[1];
                }
                // acc init from xp (bias folded by producer)
                v4f acc[4];
                acc[0][0] = __uint_as_float(A.x << 16);
                acc[1][0] = __uint_as_float(A.x & 0xffff0000u);
                acc[2][0] = __uint_as_float(A.y << 16);
                acc[3][0] = __uint_as_float(A.y & 0xffff0000u);
                acc[0][1] = __uint_as_float(A.z << 16);
                acc[1][1] = __uint_as_float(A.z & 0xffff0000u);
                acc[2][1] = __uint_as_float(A.w << 16);
                acc[3][1] = __uint_as_float(A.w & 0xffff0000u);
                acc[0][2] = __uint_as_float(Bv.x << 16);
                acc[1][2] = __uint_as_float(Bv.x & 0xffff0000u);
                acc[2][2] = __uint_as_float(Bv.y << 16);
                acc[3][2] = __uint_as_float(Bv.y & 0xffff0000u);
                acc[0][3] = __uint_as_float(Bv.z << 16);
                acc[1][3] = __uint_as_float(Bv.z & 0xffff0000u);
                acc[2][3] = __uint_as_float(Bv.w << 16);
                acc[3][3] = __uint_as_float(Bv.w & 0xffff0000u);
                // recurrent MFMA
                #pragma unroll
                for (int cls = 0; cls < 4; ++cls) {
                    acc[cls] = __builtin_amdgcn_mfma_f32_16x16x32_bf16(
                        whh[cls][0], h0, acc[cls], 0, 0, 0);
                    acc[cls] = __builtin_amdgcn_mfma_f32_16x16x32_bf16(
                        whh[cls][1], h1, acc[cls], 0, 0, 0);
                }
                // elementwise: (batch = ml, j = wv*16 + q*4 + r)
                #pragma unroll
                for (int r = 0; r < 4; ++r) {
                    float gi = sigmoidf_(acc[0][r]);
                    float gf = sigmoidf_(acc[1][r]);
                    float gg = tanhf_(acc[2][r]);
                    float go = sigmoidf_(acc[3][r]);
                    cst[r]   = fmaf(gf, cst[r], gi * gg);
                    hlast[r] = go * tanhf_(cst[r]);
                }
                // publish h(t+1)
                ushort4 hp;
                hp.x = f2bf(hlast[0]); hp.y = f2bf(hlast[1]);
                hp.z = f2bf(hlast[2]); hp.w = f2bf(hlast[3]);
                *(ushort4*)&hbf[1 - (tl & 1)][ml][wv * 16 + q * 4] = hp;
                __threadfence_block();   // release h write
                if (lane == 0) atomicAdd(&hcnt, 1u);
                const unsigned tgt = 4u * (unsigned)(t + 1);
                while (*(volatile const unsigned*)&hcnt < tgt) { }
                __threadfence_block();   // acquire others' h writes
                A = An; Bv = Bn;
            }
            __threadfence_block();
            if (lane == 0) atomicAdd(&ccnt[s], 1u);   // release slot s
        }
        // final h (f32, from registers) for the head
        float4 hv;
        hv.x = hlast[0]; hv.y = hlast[1]; hv.z = hlast[2]; hv.w = hlast[3];
        *(float4*)&hf[ml][wv * 16 + q * 4] = hv;
    }

    __syncthreads();   // all 8 waves converge (producers are done with loops)

    // ---- head: y = sigmoid(relu(h @ W1^T + b1) @ W2^T + b2) ----
    if (tid < 256) {
        const int bloc = tid & 7;        // batch 0..7
        const int j    = tid >> 3;       // 0..31
        float acc = b1[j];
        const float4* w1r = (const float4*)(W1 + (size_t)j * H_);
        #pragma unroll
        for (int k4 = 0; k4 < 16; ++k4) {
            float4 h4 = *(const float4*)&hf[bloc][k4 * 4];
            float4 w4 = w1r[k4];
            acc = fmaf(w4.x, h4.x, acc); acc = fmaf(w4.y, h4.y, acc);
            acc = fmaf(w4.z, h4.z, acc); acc = fmaf(w4.w, h4.w, acc);
        }
        ys[bloc][j] = fmaxf(acc, 0.0f);
    }
    __syncthreads();
    if (tid < BPB_) {
        float a = b2[0];
        #pragma unroll
        for (int j = 0; j < 32; ++j) a = fmaf(W2[j], ys[tid][j], a);
        out[blockIdx.x * BPB_ + tid] = sigmoidf_(a);
    }
}

extern "C" void kernel_launch(void* const* d_in, const int* in_sizes, int n_in,
                              void* d_out, int out_size, void* d_ws, size_t ws_size,
                              hipStream_t stream) {
    const float* x    = (const float*)d_in[0];
    const float* W_ih = (const float*)d_in[1];
    const float* W_hh = (const float*)d_in[2];
    const float* b_ih = (const float*)d_in[3];
    const float* b_hh = (const float*)d_in[4];
    const float* W1   = (const float*)d_in[5];
    const float* b1   = (const float*)d_in[6];
    const float* W2   = (const float*)d_in[7];
    const float* b2   = (const float*)d_in[8];
    float* out = (float*)d_out;

    lstm_pc_kernel<<<dim3(NBLK_), dim3(512), 0, stream>>>(
        x, W_ih, W_hh, b_ih, b_hh, W1, b1, W2, b2, out);
}

// Round 8
// 406.747 us; speedup vs baseline: 1.8946x; 1.8946x over previous
//
#include <hip/hip_runtime.h>
#include <math.h>

// Problem constants: B=1024, T=256, D=128, H=64, 4H=256
constexpr int B_ = 1024;
constexpr int T_ = 256;
constexpr int D_ = 128;
constexpr int H_ = 64;
constexpr int G_ = 256;
constexpr int M_ = B_ * T_;

typedef short     v8s __attribute__((ext_vector_type(8)));   // 8 bf16
typedef float     v4f __attribute__((ext_vector_type(4)));   // MFMA acc
typedef _Float16  h2  __attribute__((ext_vector_type(2)));   // packed f16

__device__ __forceinline__ float sigmoidf_(float x) {
    return 1.0f / (1.0f + __expf(-x));
}
// tanh(x) = 2*sigmoid(2x) - 1 ; overflow-safe at both ends
__device__ __forceinline__ float tanhf_(float x) {
    return fmaf(2.0f, 1.0f / (1.0f + __expf(-2.0f * x)), -1.0f);
}
__device__ __forceinline__ unsigned short f2bf(float f) {   // RNE f32->bf16
    unsigned u = __float_as_uint(f);
    u = (u + 0x7fffu + ((u >> 16) & 1u)) >> 16;
    return (unsigned short)u;
}
__device__ __forceinline__ v8s pack8(float4 a, float4 b) {
    v8s r;
    r[0] = (short)f2bf(a.x); r[1] = (short)f2bf(a.y);
    r[2] = (short)f2bf(a.z); r[3] = (short)f2bf(a.w);
    r[4] = (short)f2bf(b.x); r[5] = (short)f2bf(b.y);
    r[6] = (short)f2bf(b.z); r[7] = (short)f2bf(b.w);
    return r;
}
__device__ __forceinline__ unsigned pkh2(float a, float b) {  // 2xf32 -> packed f16
    h2 v; v[0] = (_Float16)a; v[1] = (_Float16)b;
    return __builtin_bit_cast(unsigned, v);
}
// f16x2 dot with f32 accumulate (v_dot2_f32_f16); safe fallback if missing
__device__ __forceinline__ float fdot2_(unsigned a, unsigned b, float c) {
#if __has_builtin(__builtin_amdgcn_fdot2)
    return __builtin_amdgcn_fdot2(__builtin_bit_cast(h2, a),
                                  __builtin_bit_cast(h2, b), c, false);
#else
    h2 ha = __builtin_bit_cast(h2, a), hb = __builtin_bit_cast(h2, b);
    return c + (float)ha[0] * (float)hb[0] + (float)ha[1] * (float)hb[1];
#endif
}

// ---------------------------------------------------------------------------
// Phase 1: xp[b][t][g] (f16, bias folded) = W_ih @ x^T. 1024 blocks
// (16 t x 64 batch-blocks), 256 thr. A-frags (W_ih) + bias live in wave
// registers (proven-resident v8s pattern); x staged once (read exactly once
// chip-wide); C-tiles bounced through LDS so the global store is f16
// gate-contiguous -- exactly phase 2's coalesced read layout.
// ---------------------------------------------------------------------------
__global__ __launch_bounds__(256, 2)
void xproj_f16_kernel(const float* __restrict__ x,       // [B,T,D]
                      const float* __restrict__ W_ih,    // [256,128]
                      const float* __restrict__ b_ih,    // [256]
                      const float* __restrict__ b_hh,    // [256]
                      unsigned short* __restrict__ xp)   // [B][T][256] f16
{
    const int tch  = blockIdx.x;     // 0..15 : t = tch*16 + tl
    const int bblk = blockIdx.y;     // 0..63 : batches bblk*16..+15
    const int tid  = threadIdx.x;
    const int wv   = tid >> 6;
    const int lane = tid & 63;
    const int q    = lane >> 4;
    const int ml   = lane & 15;

    __shared__ __align__(16) unsigned short xs[16][136];   // x tile bf16, pad+8
    __shared__ __align__(16) unsigned short tbuf[16][272]; // [batch][gate] f16

    // ---- wave-resident A-frags + bias: gate tiles gt = cls*4 + wv ----
    v8s afr[4][4];   // [cls][ks]
    v4f bias[4];
    #pragma unroll
    for (int cls = 0; cls < 4; ++cls) {
        const int gr = (cls * 4 + wv) * 16 + ml;       // A m-index = ml
        #pragma unroll
        for (int ks = 0; ks < 4; ++ks) {
            const float* p = W_ih + (size_t)gr * D_ + ks * 32 + q * 8;
            afr[cls][ks] = pack8(((const float4*)p)[0], ((const float4*)p)[1]);
        }
        #pragma unroll
        for (int r = 0; r < 4; ++r) {
            const int g2 = (cls * 4 + wv) * 16 + q * 4 + r;   // C row = q*4+r
            bias[cls][r] = b_ih[g2] + b_hh[g2];
        }
    }

    for (int tl = 0; tl < 16; ++tl) {
        const int t = tch * 16 + tl;

        // ---- stage x tile: 16 batches x 128 f32 -> bf16 LDS ----
        #pragma unroll
        for (int i = 0; i < 2; ++i) {
            int f4  = tid + i * 256;          // 512 float4s
            int row = f4 >> 5, c4 = f4 & 31;
            float4 v = ((const float4*)(x + ((size_t)(bblk * 16 + row) * T_
                                             + t) * D_))[c4];
            short4 s;
            s.x = (short)f2bf(v.x); s.y = (short)f2bf(v.y);
            s.z = (short)f2bf(v.z); s.w = (short)f2bf(v.w);
            *(short4*)&xs[row][c4 * 4] = s;
        }
        __syncthreads();   // bar1: xs ready (also protects prev tbuf readers)

        // ---- MFMA: 4 C-tiles per wave, K=128 ----
        v4f acc[4];
        #pragma unroll
        for (int cls = 0; cls < 4; ++cls) acc[cls] = bias[cls];
        #pragma unroll
        for (int ks = 0; ks < 4; ++ks) {
            v8s bf = *(const v8s*)&xs[ml][ks * 32 + q * 8];   // B: n=ml, k
            #pragma unroll
            for (int cls = 0; cls < 4; ++cls)
                acc[cls] = __builtin_amdgcn_mfma_f32_16x16x32_bf16(
                    afr[cls][ks], bf, acc[cls], 0, 0, 0);
        }

        // ---- pack f16 -> tbuf[batch=ml][gate] ----
        #pragma unroll
        for (int cls = 0; cls < 4; ++cls) {
            uint2 pk;
            pk.x = pkh2(acc[cls][0], acc[cls][1]);
            pk.y = pkh2(acc[cls][2], acc[cls][3]);
            *(uint2*)&tbuf[ml][cls * 64 + wv * 16 + q * 4] = pk;
        }
        __syncthreads();   // bar2: tbuf ready; all xs reads done

        // ---- coalesced store: thread covers 16 gates of one (b,t) row ----
        {
            const int br = tid >> 4, seg = tid & 15;
            uint4 r0 = *(const uint4*)&tbuf[br][seg * 16];
            uint4 r1 = *(const uint4*)&tbuf[br][seg * 16 + 8];
            unsigned short* orow = xp + ((size_t)(bblk * 16 + br) * T_ + t) * G_
                                      + seg * 16;
            *(uint4*)orow       = r0;
            *(uint4*)(orow + 8) = r1;
        }
    }
}

// ---------------------------------------------------------------------------
// Phase 2: recurrence, R2 skeleton (1024 blocks, thread g = gate row,
// 2 barriers/step, 4 blocks/CU for latency hiding) with the matvec on
// f16 dot2: 32 v_dot2_f32_f16 instead of 64 v_fma_f32. W_hh packed in
// 8 uint4 (register-resident); h as f16 in LDS, read as 8 broadcast b128s.
// ---------------------------------------------------------------------------
__global__ __launch_bounds__(256, 4)
void rec_dot2_kernel(const unsigned short* __restrict__ xp,  // [B][T][256] f16
                     const float* __restrict__ W_hh,   // [256,64]
                     const float* __restrict__ W1,     // [32,64]
                     const float* __restrict__ b1,     // [32]
                     const float* __restrict__ W2,     // [1,32]
                     const float* __restrict__ b2,     // [1]
                     float* __restrict__ out)          // [B]
{
    const int b   = blockIdx.x;
    const int g   = threadIdx.x;     // gate row 0..255
    const int cls = g >> 6;          // wave-uniform gate class

    __shared__ __align__(16) unsigned hbuf[2][32];   // h as 64 f16, dbuf
    __shared__ float gates[G_];                      // activated gates
    __shared__ float hf[H_];                         // final h f32
    __shared__ float ys[32];                         // head hidden

    // ---- W_hh row g -> 32 packed f16 pairs in 8 uint4 (resident) ----
    uint4 wp[8];
    #pragma unroll
    for (int k8 = 0; k8 < 8; ++k8) {
        const float* p = W_hh + (size_t)g * H_ + k8 * 8;
        float4 v0 = ((const float4*)p)[0];
        float4 v1 = ((const float4*)p)[1];
        wp[k8].x = pkh2(v0.x, v0.y);
        wp[k8].y = pkh2(v0.z, v0.w);
        wp[k8].z = pkh2(v1.x, v1.y);
        wp[k8].w = pkh2(v1.z, v1.w);
    }

    if (g < 32) hbuf[0][g] = 0u;     // h(0) = 0
    float c = 0.0f, hval = 0.0f;

    const unsigned short* __restrict__ xrow = xp + (size_t)b * T_ * G_ + g;
    unsigned short xv = xrow[0];
    __syncthreads();

    for (int t = 0; t < T_; ++t) {
        const int par = t & 1;
        // prefetch next step's xp element (drains at bar1, behind the matvec)
        unsigned short xn = xrow[(size_t)((t + 1 < T_) ? t + 1 : T_ - 1) * G_];

        // ---- matvec: 32 f16 dot2, f32 accumulate, 4 chains ----
        float a0 = 0.f, a1 = 0.f, a2 = 0.f, a3 = 0.f;
        const uint4* hb = (const uint4*)hbuf[par];
        #pragma unroll
        for (int k8 = 0; k8 < 8; ++k8) {
            uint4 hv = hb[k8];               // broadcast b128 (same addr)
            a0 = fdot2_(wp[k8].x, hv.x, a0);
            a1 = fdot2_(wp[k8].y, hv.y, a1);
            a2 = fdot2_(wp[k8].z, hv.z, a2);
            a3 = fdot2_(wp[k8].w, hv.w, a3);
        }
        float pre = (float)__builtin_bit_cast(_Float16, xv)
                  + ((a0 + a1) + (a2 + a3));
        gates[g] = (cls == 2) ? tanhf_(pre) : sigmoidf_(pre);
        __syncthreads();   // bar1: gates ready

        if (g < H_) {
            float gi = gates[g];
            float gf = gates[H_ + g];
            float gg = gates[2 * H_ + g];
            float go = gates[3 * H_ + g];
            c    = fmaf(gf, c, gi * gg);
            hval = go * tanhf_(c);
            ((_Float16*)hbuf[1 - par])[g] = (_Float16)hval;
        }
        __syncthreads();   // bar2: h(t+1) ready
        xv = xn;
    }

    // ---- head ----
    if (g < H_) hf[g] = hval;
    __syncthreads();
    if (g < 32) {
        float acc = b1[g];
        const float4* w1r = (const float4*)(W1 + (size_t)g * H_);
        #pragma unroll
        for (int k4 = 0; k4 < 16; ++k4) {
            float4 h4 = *(const float4*)&hf[k4 * 4];
            float4 w4 = w1r[k4];
            acc = fmaf(w4.x, h4.x, acc); acc = fmaf(w4.y, h4.y, acc);
            acc = fmaf(w4.z, h4.z, acc); acc = fmaf(w4.w, h4.w, acc);
        }
        ys[g] = fmaxf(acc, 0.0f);
    }
    __syncthreads();
    if (g == 0) {
        float acc = b2[0];
        #pragma unroll
        for (int j = 0; j < 32; ++j) acc = fmaf(W2[j], ys[j], acc);
        out[b] = sigmoidf_(acc);
    }
}

// ---------------------------------------------------------------------------
// Fallback: round-1 fused fp32 kernel (used only if workspace too small).
// ---------------------------------------------------------------------------
__global__ __launch_bounds__(256, 2)
void lstm_fused_kernel(const float* __restrict__ x,
                       const float* __restrict__ W_ih,
                       const float* __restrict__ W_hh,
                       const float* __restrict__ b_ih,
                       const float* __restrict__ b_hh,
                       const float* __restrict__ W1,
                       const float* __restrict__ b1,
                       const float* __restrict__ W2,
                       const float* __restrict__ b2,
                       float* __restrict__ out)
{
    const int b = blockIdx.x;
    const int g = threadIdx.x;

    __shared__ __align__(16) float xs[D_];
    __shared__ __align__(16) float hs[H_];
    __shared__ __align__(16) float gts[G_];
    __shared__ __align__(16) float yss[32];

    float wih[D_];
    float whhr[H_];
    {
        const float4* wr = (const float4*)(W_ih + (size_t)g * D_);
        #pragma unroll
        for (int k = 0; k < D_ / 4; ++k) {
            float4 v = wr[k];
            wih[4*k+0] = v.x; wih[4*k+1] = v.y;
            wih[4*k+2] = v.z; wih[4*k+3] = v.w;
        }
    }
    {
        const float4* wr = (const float4*)(W_hh + (size_t)g * H_);
        #pragma unroll
        for (int k = 0; k < H_ / 4; ++k) {
            float4 v = wr[k];
            whhr[4*k+0] = v.x; whhr[4*k+1] = v.y;
            whhr[4*k+2] = v.z; whhr[4*k+3] = v.w;
        }
    }
    const float bg  = b_ih[g] + b_hh[g];
    const int   cls = g >> 6;

    float c = 0.0f;
    if (g < H_) hs[g] = 0.0f;

    const float* __restrict__ xrow = x + (size_t)b * T_ * D_;

    for (int t = 0; t < T_; ++t) {
        if (g < D_) xs[g] = xrow[(size_t)t * D_ + g];
        __syncthreads();

        float a0 = bg, a1 = 0.f, a2 = 0.f, a3 = 0.f;
        const float4* xs4 = (const float4*)xs;
        #pragma unroll
        for (int k = 0; k < D_ / 4; ++k) {
            float4 v = xs4[k];
            a0 = fmaf(wih[4*k+0], v.x, a0);
            a1 = fmaf(wih[4*k+1], v.y, a1);
            a2 = fmaf(wih[4*k+2], v.z, a2);
            a3 = fmaf(wih[4*k+3], v.w, a3);
        }
        const float4* hs4 = (const float4*)hs;
        #pragma unroll
        for (int k = 0; k < H_ / 4; ++k) {
            float4 v = hs4[k];
            a0 = fmaf(whhr[4*k+0], v.x, a0);
            a1 = fmaf(whhr[4*k+1], v.y, a1);
            a2 = fmaf(whhr[4*k+2], v.z, a2);
            a3 = fmaf(whhr[4*k+3], v.w, a3);
        }
        float acc = (a0 + a1) + (a2 + a3);
        gts[g] = (cls == 2) ? tanhf_(acc) : sigmoidf_(acc);
        __syncthreads();

        if (g < H_) {
            float gi = gts[g];
            float gf = gts[H_ + g];
            float gg = gts[2 * H_ + g];
            float go = gts[3 * H_ + g];
            c = fmaf(gf, c, gi * gg);
            hs[g] = go * tanhf_(c);
        }
    }
    __syncthreads();

    if (g < 32) {
        float acc = b1[g];
        const float* w1r = W1 + g * H_;
        #pragma unroll
        for (int k = 0; k < H_; ++k) acc = fmaf(w1r[k], hs[k], acc);
        yss[g] = fmaxf(acc, 0.0f);
    }
    __syncthreads();
    if (g == 0) {
        float acc = b2[0];
        #pragma unroll
        for (int k = 0; k < 32; ++k) acc = fmaf(W2[k], yss[k], acc);
        out[b] = sigmoidf_(acc);
    }
}

extern "C" void kernel_launch(void* const* d_in, const int* in_sizes, int n_in,
                              void* d_out, int out_size, void* d_ws, size_t ws_size,
                              hipStream_t stream) {
    const float* x    = (const float*)d_in[0];
    const float* W_ih = (const float*)d_in[1];
    const float* W_hh = (const float*)d_in[2];
    const float* b_ih = (const float*)d_in[3];
    const float* b_hh = (const float*)d_in[4];
    const float* W1   = (const float*)d_in[5];
    const float* b1   = (const float*)d_in[6];
    const float* W2   = (const float*)d_in[7];
    const float* b2   = (const float*)d_in[8];
    float* out = (float*)d_out;

    const size_t xp_bytes = (size_t)M_ * G_ * sizeof(unsigned short);  // 134 MB

    if (ws_size >= xp_bytes) {
        unsigned short* xp = (unsigned short*)d_ws;
        xproj_f16_kernel<<<dim3(16, 64), dim3(256), 0, stream>>>(
            x, W_ih, b_ih, b_hh, xp);
        rec_dot2_kernel<<<dim3(B_), dim3(256), 0, stream>>>(
            xp, W_hh, W1, b1, W2, b2, out);
    } else {
        lstm_fused_kernel<<<dim3(B_), dim3(256), 0, stream>>>(
            x, W_ih, W_hh, b_ih, b_hh, W1, b1, W2, b2, out);
    }
}